// Round 6
// baseline (547.362 us; speedup 1.0000x reference)
//
#include <hip/hip_runtime.h>

#define HCDIM 292
#define NHEAD 4
#define CDIM 73
#define SLOTS 5
#define NPERM 320
#define BN_EPS 1e-5f
#define LOG2E 1.44269504f

using u16x8 = __attribute__((ext_vector_type(8))) unsigned short;
using f32x4 = __attribute__((ext_vector_type(4))) float;   // MFMA acc
using u16x4 = __attribute__((ext_vector_type(4))) unsigned short;
using hf2   = __attribute__((ext_vector_type(2))) _Float16;  // arithmetic type
using v2h   = __attribute__((ext_vector_type(2))) __fp16;    // builtin boundary
using v8h   = __attribute__((ext_vector_type(8))) __fp16;    // MFMA frag

__device__ inline v2h pkrtz(float a, float b) {              // 2xf32 -> packed f16
  return __builtin_amdgcn_cvt_pkrtz(a, b);
}
__device__ inline float fdot2(hf2 a, hf2 b, float c) {
  return __builtin_amdgcn_fdot2(__builtin_bit_cast(v2h, a),
                                __builtin_bit_cast(v2h, b), c, false);
}
__device__ inline ushort f2h(float f) {
  _Float16 h = (_Float16)f;
  return __builtin_bit_cast(ushort, h);
}
__device__ inline float h2f(ushort v) {
  return (float)__builtin_bit_cast(_Float16, v);
}
__device__ inline hf2 habs2(hf2 a) {
  unsigned u = __builtin_bit_cast(unsigned, a) & 0x7fff7fffu;
  return __builtin_bit_cast(hf2, u);
}
// single-instruction exp2 (input pre-clamped; HW flushes large-negative to 0)
__device__ inline float fexp2(float x) {
  float r;
  asm("v_exp_f32 %0, %1" : "=v"(r) : "v"(x));
  return r;
}

// ACC += f32(lo/hi f16 of U) * W  -- v_fma_mix fuses the f16->f32 convert (exact)
#define FMAMIX_LO(ACC, W, U)                                                  \
  asm("v_fma_mix_f32 %0, %1, %2, %0 op_sel_hi:[1,0,0]"                        \
      : "+v"(ACC) : "v"(U), "v"(W))
#define FMAMIX_HI(ACC, W, U)                                                  \
  asm("v_fma_mix_f32 %0, %1, %2, %0 op_sel:[1,0,0] op_sel_hi:[1,0,0]"         \
      : "+v"(ACC) : "v"(U), "v"(W))

// all-lanes sum within each 16-lane row, VALU-pipe only (DPP):
// xor1 (quad_perm [1,0,3,2]=0xB1), xor2 ([2,3,0,1]=0x4E), row_ror:4, row_ror:8
__device__ inline float dpp16_allsum(float v) {
  union { float f; int i; } a, b;
  a.f = v;
  b.i = __builtin_amdgcn_update_dpp(0, a.i, 0xB1, 0xf, 0xf, true);
  a.f += b.f;
  b.i = __builtin_amdgcn_update_dpp(0, a.i, 0x4E, 0xf, 0xf, true);
  a.f += b.f;
  b.i = __builtin_amdgcn_update_dpp(0, a.i, 0x124, 0xf, 0xf, true);
  a.f += b.f;
  b.i = __builtin_amdgcn_update_dpp(0, a.i, 0x128, 0xf, 0xf, true);
  a.f += b.f;
  return a.f;
}

// permuted slot p -> original feature index (h*73+c); valid=false for 28 dead slots
__device__ inline int perm2feat(int p, bool& valid) {
  int h, c;
  if (p < 256) {
    h = p >> 6;
    c = ((p & 3) << 4) | ((p >> 2) & 15);
    valid = true;
  } else {
    int q = p - 256;
    h = q >> 4;
    c = 64 + (q & 15);
    valid = (q & 15) < (CDIM - 64);
  }
  return h * CDIM + c;
}

// ======================= weight / vector prep =======================
// y=0: W0/b0 -> Wp cols [0,320); y=1: W1/b1 -> cols [320,640)
// y=2 (L1 launch only): permute the 8 small vectors into o (was k_vecperm)
__global__ void k_wperm2(const float* __restrict__ W0, const float* __restrict__ b0,
                         const float* __restrict__ W1, const float* __restrict__ b1,
                         ushort* __restrict__ Wp, float* __restrict__ pb,
                         int Kin, int Kpad, int kperm,
                         const float* __restrict__ att1, const float* __restrict__ b1v,
                         const float* __restrict__ att2, const float* __restrict__ b2v,
                         const float* __restrict__ gamma, const float* __restrict__ beta,
                         const float* __restrict__ Wc, float* __restrict__ o) {
  int p = blockIdx.x, t = threadIdx.x;
  if (blockIdx.y == 2) {
    bool pv;
    int gn = perm2feat(p, pv);
    if (t < 8) {
      const float* src;
      switch (t) {
        case 0: src = att1; break;
        case 1: src = b1v; break;
        case 2: src = att2; break;
        case 3: src = b2v; break;
        case 4: src = gamma; break;
        case 5: src = beta; break;
        case 6: src = Wc; break;
        default: src = Wc + HCDIM; break;
      }
      o[t * NPERM + p] = pv ? src[gn] : 0.f;
    }
    return;
  }
  const float* W = blockIdx.y ? W1 : W0;
  const float* b = blockIdx.y ? b1 : b0;
  ushort* Wpo = Wp + (size_t)blockIdx.y * NPERM * Kpad;
  float* pbo = pb + blockIdx.y * NPERM;
  bool pv;
  int gn = perm2feat(p, pv);
  int gk = t;
  bool kv = t < Kin;
  if (kperm) { bool v2; gk = perm2feat(t, v2); kv = v2; }
  ushort v = 0;
  if (pv && kv) v = f2h(W[(size_t)gn * Kin + gk]);
  Wpo[(size_t)p * Kpad + t] = v;
  if (t == 0) pbo[p] = pv ? b[gn] : 0.f;
}

// ======================= CSR build =======================
__global__ void k_hist(const int* __restrict__ dst, int* __restrict__ deg, int E) {
  int i = blockIdx.x * blockDim.x + threadIdx.x;
  int i4 = i * 4;
  if (i4 + 3 < E) {
    int4 d = *(const int4*)(dst + i4);
    atomicAdd(&deg[d.x], 1);
    atomicAdd(&deg[d.y], 1);
    atomicAdd(&deg[d.z], 1);
    atomicAdd(&deg[d.w], 1);
  } else {
    for (int k = i4; k < E; ++k) atomicAdd(&deg[dst[k]], 1);
  }
}

__global__ __launch_bounds__(256) void k_block_sum(const int* __restrict__ deg,
                                                   int* __restrict__ bsum, int n) {
  __shared__ int s[256];
  int i = blockIdx.x * 256 + threadIdx.x;
  s[threadIdx.x] = (i < n) ? deg[i] : 0;
  __syncthreads();
  for (int off = 128; off > 0; off >>= 1) {
    if (threadIdx.x < off) s[threadIdx.x] += s[threadIdx.x + off];
    __syncthreads();
  }
  if (threadIdx.x == 0) bsum[blockIdx.x] = s[0];
}

__global__ __launch_bounds__(256) void k_scan_small(const int* __restrict__ bsum,
                                                    int* __restrict__ boff, int G) {
  __shared__ int s[256];
  int t = threadIdx.x;
  int v = (t < G) ? bsum[t] : 0;
  s[t] = v;
  __syncthreads();
  for (int off = 1; off < 256; off <<= 1) {
    int tv = (t >= off) ? s[t - off] : 0;
    __syncthreads();
    s[t] += tv;
    __syncthreads();
  }
  if (t < G) boff[t] = s[t] - v;
}

__global__ __launch_bounds__(256) void k_scan_final(const int* __restrict__ deg,
                                                    const int* __restrict__ boff,
                                                    int* __restrict__ row_ptr,
                                                    int* __restrict__ cursor,
                                                    int n, int E) {
  __shared__ int s[256];
  int t = threadIdx.x;
  int i = blockIdx.x * 256 + t;
  int v = (i < n) ? deg[i] : 0;
  s[t] = v;
  __syncthreads();
  for (int off = 1; off < 256; off <<= 1) {
    int tv = (t >= off) ? s[t - off] : 0;
    __syncthreads();
    s[t] += tv;
    __syncthreads();
  }
  if (i < n) {
    int rp = boff[blockIdx.x] + s[t] - v;
    row_ptr[i] = rp;
    cursor[i] = rp;
  }
  if (i == 0) row_ptr[n] = E;
}

__global__ void k_csr_fill(const int* __restrict__ srcs, const int* __restrict__ dsts,
                           int* __restrict__ cursor, int* __restrict__ csr_src, int E) {
  int i = blockIdx.x * blockDim.x + threadIdx.x;
  int i4 = i * 4;
  if (i4 + 3 < E) {
    int4 s = *(const int4*)(srcs + i4);
    int4 d = *(const int4*)(dsts + i4);
    csr_src[atomicAdd(&cursor[d.x], 1)] = s.x;
    csr_src[atomicAdd(&cursor[d.y], 1)] = s.y;
    csr_src[atomicAdd(&cursor[d.z], 1)] = s.z;
    csr_src[atomicAdd(&cursor[d.w], 1)] = s.w;
  } else {
    for (int k = i4; k < E; ++k) {
      int pos = atomicAdd(&cursor[dsts[k]], 1);
      csr_src[pos] = srcs[k];
    }
  }
}

// ======================= A-in-LDS GEMM (B streamed from L2) =======================
// Block: 64 rows x ALL 640 cols (both xl and xr halves from ONE staged A tile).
template <int KS, int MODE>
__global__ __launch_bounds__(256, 4) void k_gemm_a_lds(
    const void* __restrict__ Av, const ushort* __restrict__ Wb,
    const float* __restrict__ pb, const float* __restrict__ bnscale,
    const float* __restrict__ bnshift, ushort* __restrict__ o0,
    ushort* __restrict__ o1, int M) {
  constexpr int KSTEPS = KS / 32;
  constexpr int STR = KS + 8;          // pad: row stride 4 banks apart -> 2-way max
  __shared__ ushort As[64 * STR];
  const int tid = threadIdx.x;
  const int rbase = blockIdx.x * 64;
  const int wave = tid >> 6, lane = tid & 63;
  const int quad = lane >> 4, lr = lane & 15;
  const int ct = wave;                 // 80-col slice within each 320-col half

  // ---- stage A tile (64 x KS) into LDS ----
  if constexpr (MODE == 0) {
    const float* X = (const float*)Av;
    constexpr int NIT = (64 * KS / 16) / 256;  // 16-float segments per thread
#pragma unroll
    for (int k = 0; k < NIT; ++k) {
      int idx = tid + k * 256;
      int row = idx >> 3, sg = idx & 7;        // KS=128 -> 8 segs/row
      int gr = rbase + row;
      if (gr >= M) gr = M - 1;
      const float4* p = (const float4*)(X + (size_t)gr * KS + sg * 16);
      float4 f0 = p[0], f1 = p[1], f2 = p[2], f3 = p[3];
      union { v2h h[4]; u16x8 v; } a, b;
      a.h[0] = pkrtz(f0.x, f0.y); a.h[1] = pkrtz(f0.z, f0.w);
      a.h[2] = pkrtz(f1.x, f1.y); a.h[3] = pkrtz(f1.z, f1.w);
      b.h[0] = pkrtz(f2.x, f2.y); b.h[1] = pkrtz(f2.z, f2.w);
      b.h[2] = pkrtz(f3.x, f3.y); b.h[3] = pkrtz(f3.z, f3.w);
      *(u16x8*)(As + row * STR + sg * 16) = a.v;
      *(u16x8*)(As + row * STR + sg * 16 + 8) = b.v;
    }
  } else {
    const ushort* Hn = (const ushort*)Av;
    constexpr int NIT = (64 * KS / 8) / 256;   // 8-elem segments per thread
#pragma unroll
    for (int k = 0; k < NIT; ++k) {
      int idx = tid + k * 256;
      int row = idx / (KS / 8), c8 = idx - row * (KS / 8);
      int gr = rbase + row;
      if (gr >= M) gr = M - 1;
      u16x8 v = *(const u16x8*)(Hn + (size_t)gr * KS + c8 * 8);
      int c = c8 * 8;
      float4 s0 = *(const float4*)(bnscale + c);
      float4 s1 = *(const float4*)(bnscale + c + 4);
      float4 t0 = *(const float4*)(bnshift + c);
      float4 t1 = *(const float4*)(bnshift + c + 4);
      float f[8];
      f[0] = fmaf(h2f(v[0]), s0.x, t0.x);
      f[1] = fmaf(h2f(v[1]), s0.y, t0.y);
      f[2] = fmaf(h2f(v[2]), s0.z, t0.z);
      f[3] = fmaf(h2f(v[3]), s0.w, t0.w);
      f[4] = fmaf(h2f(v[4]), s1.x, t1.x);
      f[5] = fmaf(h2f(v[5]), s1.y, t1.y);
      f[6] = fmaf(h2f(v[6]), s1.z, t1.z);
      f[7] = fmaf(h2f(v[7]), s1.w, t1.w);
#pragma unroll
      for (int j = 0; j < 8; ++j) f[j] = (f[j] > 0.f) ? f[j] : 0.01f * f[j];
      union { v2h h4[4]; u16x8 o; } u;
#pragma unroll
      for (int j = 0; j < 4; ++j) u.h4[j] = pkrtz(f[2 * j], f[2 * j + 1]);
      *(u16x8*)(As + row * STR + c8 * 8) = u.o;
    }
  }
  __syncthreads();

  const ushort* arow[4];
#pragma unroll
  for (int i = 0; i < 4; ++i) arow[i] = As + (i * 16 + lr) * STR;

#pragma unroll
  for (int y = 0; y < 2; ++y) {
    const ushort* bcol[5];
#pragma unroll
    for (int i = 0; i < 5; ++i)
      bcol[i] = Wb + (size_t)(y * 320 + ct * 80 + i * 16 + lr) * KS;

    f32x4 acc[4][5] = {};
#pragma unroll
    for (int s = 0; s < KSTEPS; ++s) {
      v8h bf[5], af[4];
#pragma unroll
      for (int i = 0; i < 5; ++i)
        bf[i] = *(const v8h*)(bcol[i] + s * 32 + quad * 8);
#pragma unroll
      for (int i = 0; i < 4; ++i)
        af[i] = *(const v8h*)(arow[i] + s * 32 + quad * 8);
#pragma unroll
      for (int ni = 0; ni < 5; ++ni)
#pragma unroll
        for (int mi = 0; mi < 4; ++mi)   // bf first: acc regs index 4 consecutive n
          acc[mi][ni] = __builtin_amdgcn_mfma_f32_16x16x32_f16(
              bf[ni], af[mi], acc[mi][ni], 0, 0, 0);
    }

    ushort* out = y ? o1 : o0;
    const int colbase = ct * 80;
    float4 pbv[5];
#pragma unroll
    for (int ni = 0; ni < 5; ++ni)
      pbv[ni] = *(const float4*)(pb + y * 320 + ct * 80 + ni * 16 + quad * 4);
#pragma unroll
    for (int mi = 0; mi < 4; ++mi) {
      int gm = rbase + mi * 16 + lr;
      if (gm >= M) continue;
      ushort* orow = out + (size_t)gm * NPERM + colbase + quad * 4;
#pragma unroll
      for (int ni = 0; ni < 5; ++ni) {
        union { v2h h[2]; u16x4 o; } u;
        u.h[0] = pkrtz(acc[mi][ni][0] + pbv[ni].x, acc[mi][ni][1] + pbv[ni].y);
        u.h[1] = pkrtz(acc[mi][ni][2] + pbv[ni].z, acc[mi][ni][3] + pbv[ni].w);
        *(u16x4*)(orow + ni * 16) = u.o;
      }
    }
  }
}

// ======================= fused GATv2 attention =======================
// Per-edge cost trimmed: (a) single DPP allsum of z = T + 1.5*Tl (linearity of the
// 16-lane reduce), (b) v_fma_mix accumulation reads f16 halves directly (no cvt).
__global__ __launch_bounds__(128) void k_agg(const ushort* __restrict__ xl,
                                             const ushort* __restrict__ xr,
                                             const int* __restrict__ csr_src,
                                             const int* __restrict__ row_ptr,
                                             const float* __restrict__ attp,
                                             const float* __restrict__ bp,
                                             ushort* __restrict__ out, int n) {
  int wave = threadIdx.x >> 6, lane = threadIdx.x & 63;
  int d = blockIdx.x * 2 + wave;
  if (d >= n) return;
  int start = __builtin_amdgcn_readfirstlane(row_ptr[d]);
  int end = __builtin_amdgcn_readfirstlane(row_ptr[d + 1]);

  float4 bp4 = *(const float4*)(bp + lane * 4);
  float bp5 = bp[256 + lane];

  if (start >= end) {                      // isolated node -> bias only
    union { v2h h[2]; u16x4 o; } u;
    u.h[0] = pkrtz(bp4.x, bp4.y);
    u.h[1] = pkrtz(bp4.z, bp4.w);
    *(u16x4*)(out + (size_t)d * NPERM + lane * 4) = u.o;
    out[(size_t)d * NPERM + 256 + lane] = f2h(bp5);
    return;
  }

  const float C = 0.4f * LOG2E;
  float4 at4 = *(const float4*)(attp + lane * 4);
  hf2 av01{(_Float16)(C * at4.x), (_Float16)(C * at4.y)};
  hf2 av23{(_Float16)(C * at4.z), (_Float16)(C * at4.w)};
  hf2 av5{(_Float16)(C * attp[256 + lane]), (_Float16)0.f};

  hf2 xr01, xr23, xr5;
  {
    uint2 rr = *(const uint2*)(xr + (size_t)d * NPERM + lane * 4);
    xr01 = __builtin_bit_cast(hf2, rr.x);
    xr23 = __builtin_bit_cast(hf2, rr.y);
    xr5 = hf2{__builtin_bit_cast(_Float16, xr[(size_t)d * NPERM + 256 + lane]),
              (_Float16)0.f};
  }
  float Tb = fdot2(xr01, av01, fdot2(xr23, av23, fdot2(xr5, av5, 0.f)));
  Tb = dpp16_allsum(Tb);
  float prv = 1.5f * Tb;
  float acc[SLOTS] = {};
  float den = 0.f;
  int dg = end - start;
  int nfull = dg >> 2;
  int rem = dg & 3;

  // 4-slot edge pipeline, ALL indices compile-time (arrays stay in VGPRs)
  uint2 s8[4];
  ushort s1[4];
#pragma unroll
  for (int k = 0; k < 4; ++k) {
    int e = start + k;
    if (e > end - 1) e = end - 1;
    int s = __builtin_amdgcn_readfirstlane(csr_src[e]);
    s8[k] = *(const uint2*)(xl + (size_t)s * NPERM + lane * 4);
    s1[k] = xl[(size_t)s * NPERM + 256 + lane];
  }

  for (int g = 0; g < nfull; ++g) {
    int ebase = start + g * 4 + 4;
    uint2 n8[4];
    ushort n1[4];
#pragma unroll
    for (int k = 0; k < 4; ++k) {
      int e = ebase + k;
      if (e > end - 1) e = end - 1;
      int s = __builtin_amdgcn_readfirstlane(csr_src[e]);
      n8[k] = *(const uint2*)(xl + (size_t)s * NPERM + lane * 4);
      n1[k] = xl[(size_t)s * NPERM + 256 + lane];
    }

    float z[4];
#pragma unroll
    for (int k = 0; k < 4; ++k) {
      hf2 x01 = __builtin_bit_cast(hf2, s8[k].x);
      hf2 x23 = __builtin_bit_cast(hf2, s8[k].y);
      hf2 x5{__builtin_bit_cast(_Float16, s1[k]), (_Float16)0.f};
      float T = fdot2(habs2(x01 + xr01), av01,
                fdot2(habs2(x23 + xr23), av23,
                fdot2(habs2(x5 + xr5), av5, 0.f)));
      float Tl = fdot2(x01, av01, fdot2(x23, av23, fdot2(x5, av5, 0.f)));
      z[k] = fmaf(1.5f, Tl, T);
    }
#pragma unroll
    for (int k = 0; k < 4; ++k) z[k] = dpp16_allsum(z[k]);
    float w[4];
#pragma unroll
    for (int k = 0; k < 4; ++k) {
      w[k] = fexp2(fminf(z[k] + prv, 80.f));
      den += w[k];
    }
#pragma unroll
    for (int k = 0; k < 4; ++k) {
      unsigned ux = s8[k].x, uy = s8[k].y, u5 = (unsigned)s1[k];
      FMAMIX_LO(acc[0], w[k], ux);
      FMAMIX_HI(acc[1], w[k], ux);
      FMAMIX_LO(acc[2], w[k], uy);
      FMAMIX_HI(acc[3], w[k], uy);
      FMAMIX_LO(acc[4], w[k], u5);
    }
#pragma unroll
    for (int k = 0; k < 4; ++k) { s8[k] = n8[k]; s1[k] = n1[k]; }
  }

  // tail: unrolled + predicated -> static indices only
#pragma unroll
  for (int k = 0; k < 3; ++k) {
    if (k < rem) {
      hf2 x01 = __builtin_bit_cast(hf2, s8[k].x);
      hf2 x23 = __builtin_bit_cast(hf2, s8[k].y);
      hf2 x5{__builtin_bit_cast(_Float16, s1[k]), (_Float16)0.f};
      float T = fdot2(habs2(x01 + xr01), av01,
                fdot2(habs2(x23 + xr23), av23,
                fdot2(habs2(x5 + xr5), av5, 0.f)));
      float Tl = fdot2(x01, av01, fdot2(x23, av23, fdot2(x5, av5, 0.f)));
      float z = fmaf(1.5f, Tl, T);
      z = dpp16_allsum(z);
      float w = fexp2(fminf(z + prv, 80.f));
      den += w;
      unsigned ux = s8[k].x, uy = s8[k].y, u5 = (unsigned)s1[k];
      FMAMIX_LO(acc[0], w, ux);
      FMAMIX_HI(acc[1], w, ux);
      FMAMIX_LO(acc[2], w, uy);
      FMAMIX_HI(acc[3], w, uy);
      FMAMIX_LO(acc[4], w, u5);
    }
  }

  float inv = 1.f / (den + 1e-16f);
  union { v2h h[2]; u16x4 o; } u;
  u.h[0] = pkrtz(fmaf(acc[0], inv, bp4.x), fmaf(acc[1], inv, bp4.y));
  u.h[1] = pkrtz(fmaf(acc[2], inv, bp4.z), fmaf(acc[3], inv, bp4.w));
  *(u16x4*)(out + (size_t)d * NPERM + lane * 4) = u.o;
  out[(size_t)d * NPERM + 256 + lane] = f2h(fmaf(acc[4], inv, bp5));
}

// ======================= BatchNorm (permuted f16 h) =======================
__global__ __launch_bounds__(320) void k_bn_reduce(const ushort* __restrict__ h,
                                                   float* __restrict__ colsum,
                                                   float* __restrict__ colsq,
                                                   int n, int rows_per_block) {
  int c = threadIdx.x;
  int r0 = blockIdx.x * rows_per_block;
  int r1 = min(r0 + rows_per_block, n);
  float s = 0.f, s2 = 0.f;
  for (int r = r0; r < r1; ++r) {
    float v = h2f(h[(size_t)r * NPERM + c]);
    s += v;
    s2 += v * v;
  }
  atomicAdd(&colsum[c], s);
  atomicAdd(&colsq[c], s2);
}

__global__ void k_bn_coef(float* __restrict__ colsum, float* __restrict__ colsq,
                          const float* __restrict__ gp, const float* __restrict__ bp,
                          float invN) {
  int c = threadIdx.x + blockIdx.x * blockDim.x;
  if (c >= NPERM) return;
  float mu = colsum[c] * invN;
  float var = colsq[c] * invN - mu * mu;
  float scale = rsqrtf(var + BN_EPS) * gp[c];
  colsum[c] = scale;
  colsq[c] = bp[c] - mu * scale;
}

// ======================= fused BN + leaky-relu + classifier =======================
__global__ __launch_bounds__(256) void k_bn_classifier(
    const ushort* __restrict__ h, const float* __restrict__ scale,
    const float* __restrict__ shift, const float* __restrict__ wc0,
    const float* __restrict__ wc1, const float* __restrict__ bc,
    float* __restrict__ out, int n) {
  int wave = threadIdx.x >> 6, lane = threadIdx.x & 63;
  int r = blockIdx.x * 4 + wave;
  if (r >= n) return;
  float a0 = 0.f, a1 = 0.f;
#pragma unroll
  for (int k = 0; k < SLOTS; ++k) {
    int slot = lane + 64 * k;
    float v = fmaf(h2f(h[(size_t)r * NPERM + slot]), scale[slot], shift[slot]);
    v = (v > 0.f) ? v : 0.01f * v;
    a0 = fmaf(v, wc0[slot], a0);
    a1 = fmaf(v, wc1[slot], a1);
  }
#pragma unroll
  for (int off = 32; off > 0; off >>= 1) {
    a0 += __shfl_xor(a0, off, 64);
    a1 += __shfl_xor(a1, off, 64);
  }
  if (lane == 0) {
    out[(size_t)2 * r] = a0 + bc[0];
    out[(size_t)2 * r + 1] = a1 + bc[1];
  }
}

// ======================= host launch =======================
extern "C" void kernel_launch(void* const* d_in, const int* in_sizes, int n_in,
                              void* d_out, int out_size, void* d_ws, size_t ws_size,
                              hipStream_t stream) {
  const float* x      = (const float*)d_in[0];
  const int*   eidx   = (const int*)d_in[1];
  const float* Wl1    = (const float*)d_in[2];
  const float* bl1    = (const float*)d_in[3];
  const float* Wr1    = (const float*)d_in[4];
  const float* br1    = (const float*)d_in[5];
  const float* att1   = (const float*)d_in[6];
  const float* b1     = (const float*)d_in[7];
  const float* Wl2    = (const float*)d_in[8];
  const float* bl2    = (const float*)d_in[9];
  const float* Wr2    = (const float*)d_in[10];
  const float* br2    = (const float*)d_in[11];
  const float* att2   = (const float*)d_in[12];
  const float* b2     = (const float*)d_in[13];
  const float* gamma  = (const float*)d_in[14];
  const float* beta   = (const float*)d_in[15];
  const float* Wc     = (const float*)d_in[16];
  const float* bc     = (const float*)d_in[17];
  float* out = (float*)d_out;

  const int FIN = 128;
  const int N = in_sizes[0] / FIN;   // 50000
  const int E = in_sizes[1] / 2;     // 800000

  const int* src = eidx;
  const int* dst = eidx + E;

  // ---- workspace layout (16B-aligned; unchanged from previous version) ----
  ushort* h      = (ushort*)d_ws;                 // N*320 f16 permuted
  ushort* xl     = h + (size_t)N * NPERM;         // N*320
  ushort* xr     = xl + (size_t)N * NPERM;        // N*320
  ushort* abuf   = xr + (size_t)N * NPERM;        // N*320 (unused; layout kept)
  ushort* wb     = abuf + (size_t)N * NPERM;      // 640*320 combined Wl|Wr
  float* pb      = (float*)(wb + (size_t)2 * NPERM * NPERM);  // 640
  float* vecp    = pb + 2 * NPERM;                // 8*320
  float* pl      = vecp + 8 * NPERM;              // N*4 (unused; layout kept)
  float* colsum  = pl + (size_t)N * NHEAD;        // 320 (-> scale)
  float* colsq   = colsum + NPERM;                // 320 (-> shift)
  int* deg       = (int*)(colsq + NPERM);
  int* row_ptr   = deg + N;                       // N+1
  int* cursor    = row_ptr + N + 1;
  int* bsum      = cursor + N;                    // 256
  int* boff      = bsum + 256;                    // 256
  int* csr_src   = boff + 256;                    // E

  const int G = (N + 255) / 256;
  const int EB4 = (E / 4 + 255) / 256;
  const int AGGB = (N + 3) / 4;
  const int AGG2 = (N + 1) / 2;
  const int GEMMB = (N + 63) / 64;

  const float* att1p = vecp;
  const float* b1p   = vecp + NPERM;
  const float* att2p = vecp + 2 * NPERM;
  const float* b2p   = vecp + 3 * NPERM;
  const float* gp    = vecp + 4 * NPERM;
  const float* btp   = vecp + 5 * NPERM;
  const float* wc0   = vecp + 6 * NPERM;
  const float* wc1   = vecp + 7 * NPERM;

  // ---- CSR build ----
  hipMemsetAsync(deg, 0, (size_t)N * sizeof(int), stream);
  k_hist<<<EB4, 256, 0, stream>>>(dst, deg, E);
  k_block_sum<<<G, 256, 0, stream>>>(deg, bsum, N);
  k_scan_small<<<1, 256, 0, stream>>>(bsum, boff, G);
  k_scan_final<<<G, 256, 0, stream>>>(deg, boff, row_ptr, cursor, N, E);
  k_csr_fill<<<EB4, 256, 0, stream>>>(src, dst, cursor, csr_src, E);

  // ---- layer 1 (A = x fp32, converted during LDS staging; y==2 does vecperm) ----
  k_wperm2<<<dim3(NPERM, 3), FIN, 0, stream>>>(Wl1, bl1, Wr1, br1, wb, pb,
                                               FIN, FIN, 0,
                                               att1, b1, att2, b2, gamma, beta,
                                               Wc, vecp);
  k_gemm_a_lds<128, 0><<<GEMMB, 256, 0, stream>>>((const void*)x, wb, pb,
                                                  nullptr, nullptr, xl, xr, N);
  k_agg<<<AGG2, 128, 0, stream>>>(xl, xr, csr_src, row_ptr, att1p, b1p, h, N);

  const int BNB = 1024;
  const int RPB = (N + BNB - 1) / BNB;
  hipMemsetAsync(colsum, 0, 2 * NPERM * sizeof(float), stream);
  k_bn_reduce<<<BNB, NPERM, 0, stream>>>(h, colsum, colsq, N, RPB);
  k_bn_coef<<<2, 160, 0, stream>>>(colsum, colsq, gp, btp, 1.f / (float)N);

  // ---- layer 2 (A = h f16; BN+leaky fused into GEMM A-staging) ----
  k_wperm2<<<dim3(NPERM, 2), NPERM, 0, stream>>>(Wl2, bl2, Wr2, br2, wb, pb,
                                                 HCDIM, NPERM, 1,
                                                 nullptr, nullptr, nullptr, nullptr,
                                                 nullptr, nullptr, nullptr, nullptr);
  k_gemm_a_lds<NPERM, 1><<<GEMMB, 256, 0, stream>>>((const void*)h, wb, pb,
                                                    colsum, colsq, xl, xr, N);
  k_agg<<<AGG2, 128, 0, stream>>>(xl, xr, csr_src, row_ptr, att2p, b2p, h, N);

  hipMemsetAsync(colsum, 0, 2 * NPERM * sizeof(float), stream);
  k_bn_reduce<<<BNB, NPERM, 0, stream>>>(h, colsum, colsq, N, RPB);
  k_bn_coef<<<2, 160, 0, stream>>>(colsum, colsq, gp, btp, 1.f / (float)N);

  // ---- fused BN + classifier ----
  k_bn_classifier<<<AGGB, 256, 0, stream>>>(h, colsum, colsq, wc0, wc1, bc, out, N);
}